// Round 12
// baseline (141.316 us; speedup 1.0000x reference)
//
#include <hip/hip_runtime.h>
#include <hip/hip_bf16.h>
#include <stdint.h>
#include <stddef.h>

// MHA fwd: B=2 S=2048 D=1024 H=16 DK=64.
// wt (W->Wt bf16) -> gemm_qkv (fp32-A via global_load_lds, TRIPLE-buffered
// counted-vmcnt pipeline, 2 barriers/step, hf-XOR bank-free layout) ->
// flash (R8 2-stage S-pipeline + 64B-row conflict-free K/V layout) ->
// gemm_o (64x128).
//
// R12: R11 held best (124.85) and flash's conflict fix landed (flash left
// top-5), but qkv's conflicts were bit-identical (3.15M): the A-read chunk
// used only g&1, so g=0/2 and g=1/3 hit the same banks (k-half bit = +2048
// dwords = 0 mod 32). Fix: pc = cc ^ rsw ^ hf -> all 4 g-groups disjoint.
// Structural: qkv was 2-phase (tile t+1's loads get only ~250cy of cover,
// then __syncthreads drains vmcnt(0)) -> 400 TF. Now flash-style counted
// vmcnt with stage-ahead-2: STAGE(t+2); vmcnt(12); barrier; compute(t);
// barrier. Mod-3 buffers need the 2nd barrier (write (t+3)%3==t%3 would
// race the slowest reader with only one). ~2 steps (~500cy) of cover vs
// L2-resident A/W latency (~200cy). LDS 72KB -> 2 blocks/CU.

typedef __bf16 bf16;
typedef __attribute__((ext_vector_type(4))) bf16 bf16x4;
typedef __attribute__((ext_vector_type(8))) bf16 bf16x8;
typedef __attribute__((ext_vector_type(4))) float f32x4;
typedef __attribute__((ext_vector_type(16))) float f32x16;
typedef __attribute__((ext_vector_type(2))) unsigned int uint2v;

#define DEVINL static __device__ __forceinline__

DEVINL void gload_lds16(const void* g, void* l) {
  __builtin_amdgcn_global_load_lds(
      (const __attribute__((address_space(1))) void*)g,
      (__attribute__((address_space(3))) void*)l, 16, 0, 0);
}

DEVINL f32x4 mfma16(bf16x8 a, bf16x8 b, f32x4 c) {
  return __builtin_amdgcn_mfma_f32_16x16x32_bf16(a, b, c, 0, 0, 0);
}
DEVINL f32x16 mfma32(bf16x8 a, bf16x8 b, f32x16 c) {
  return __builtin_amdgcn_mfma_f32_32x32x16_bf16(a, b, c, 0, 0, 0);
}
// v_exp_f32 computes 2^x; log2(e) is folded into the Q pre-scale.
DEVINL float fexp2(float x) {
  float r;
  asm("v_exp_f32 %0, %1" : "=v"(r) : "v"(x));
  return r;
}
// RNE f32->bf16 pair pack via compiler casts (m240: don't hand-write cvt_pk).
DEVINL unsigned pack2(float lo, float hi) {
  union { bf16 h[2]; unsigned u; } t;
  t.h[0] = (bf16)lo; t.h[1] = (bf16)hi;
  return t.u;
}
DEVINL bf16x8 mk8(unsigned a, unsigned b, unsigned c, unsigned d) {
  union { unsigned u[4]; bf16x8 v; } t;
  t.u[0] = a; t.u[1] = b; t.u[2] = c; t.u[3] = d;
  return t.v;
}

// ---------------------------------------------------------------------------
// Kernel 1: weight transpose+convert. W[k][n] fp32 -> Wt[t][n][k] bf16
// ---------------------------------------------------------------------------
__global__ __launch_bounds__(256) void wt_kernel(
    const float* __restrict__ w0, const float* __restrict__ w1,
    const float* __restrict__ w2, const float* __restrict__ w3,
    bf16* __restrict__ out) {
  __shared__ float tile[64 * 65];
  int t = blockIdx.y;
  const float* w = (t == 0) ? w0 : (t == 1) ? w1 : (t == 2) ? w2 : w3;
  bf16* o = out + (size_t)t * 1024 * 1024;
  int tb = blockIdx.x;
  int k0 = (tb >> 4) * 64, n0 = (tb & 15) * 64;
  int c = threadIdx.x & 63, r0 = threadIdx.x >> 6;
  for (int r = r0; r < 64; r += 4)
    tile[r * 65 + c] = w[(size_t)(k0 + r) * 1024 + n0 + c];
  __syncthreads();
  for (int r = r0; r < 64; r += 4)
    o[(size_t)(n0 + r) * 1024 + k0 + c] = (bf16)tile[c * 65 + r];
}

// ---------------------------------------------------------------------------
// Kernel 2: QKV projection GEMM. A = fp32 staged via global_load_lds into
// [hf][128 r][16 f32] tiles with pc = cc ^ ((r>>1)&3) ^ hf (bank-free for
// the fragment reads); in-reg cvt to bf16 after ds_read. B = bf16 Wt.
// TRIPLE-buffered, counted vmcnt(12), stage-ahead-2, 2 barriers/step.
// Q scaled by 0.125*log2e in epilogue -> Qp; K -> Kp; V transposed -> Vt.
// ---------------------------------------------------------------------------
__global__ __launch_bounds__(256) void gemm_qkv(
    const float* __restrict__ Aq, const float* __restrict__ Ak,
    const float* __restrict__ Av, const bf16* __restrict__ Wt,
    const float* __restrict__ bq, const float* __restrict__ bk,
    const float* __restrict__ bv,
    bf16* __restrict__ outQ, bf16* __restrict__ outK, bf16* __restrict__ Vt) {
  int z = blockIdx.z;
  const float* A   = (z == 0) ? Aq : (z == 1) ? Ak : Av;
  const bf16* Wz   = Wt + (size_t)z * 1024 * 1024;
  const float* bia = (z == 0) ? bq : (z == 1) ? bk : bv;
  float scale      = (z == 0) ? 0.18033688011112042f : 1.0f;  // 0.125*log2(e)

  __shared__ float Af[3][4096];       // [hf][128 r][16 f32], 16KB each
  __shared__ bf16  Bs[3][128 * 32];   // 8KB each; total 72KB

  int m0 = blockIdx.x * 128, n0 = blockIdx.y * 128;
  int tid = threadIdx.x, w = tid >> 6, l = tid & 63;
  int wm = (w >> 1) * 64, wn = (w & 1) * 64;
  int c16 = l & 15, g = l >> 4;
  int rsw = (c16 >> 1) & 3;           // read-side row swizzle
  int ghf = g >> 1;                   // k-half of this lane group

  // A staging: 1024 16B-units; unit u: hf=u>>9, r=(u>>2)&127, pc=u&3,
  // logical chunk cc = pc ^ ((r>>1)&3) ^ hf; src floats = kt + hf*16 + cc*4.
  int ua[4], ar[4], aso[4];
#pragma unroll
  for (int i = 0; i < 4; ++i) {
    ua[i] = (w * 4 + i) * 64 + l;
    int hf = ua[i] >> 9;
    int rr = (ua[i] >> 2) & 127;
    int cc = (ua[i] & 3) ^ ((rr >> 1) & 3) ^ hf;
    ar[i] = rr;
    aso[i] = hf * 16 + cc * 4;
  }
  // B staging: 2 units/thread, pre-swizzled global k-chunk (unchanged)
  int brow0 = (w * 2 + 0) * 16 + (l >> 2);
  int brow1 = (w * 2 + 1) * 16 + (l >> 2);
  int bk0 = ((l & 3) ^ ((brow0 >> 1) & 3)) * 8;
  int bk1 = ((l & 3) ^ ((brow1 >> 1) & 3)) * 8;

  f32x4 acc[4][4] = {};

  // issue order: 4x A, 2x B = 6 loads/STAGE (vmcnt counting relies on this)
#define STAGE_QKV(buf, kt)                                                   \
  do {                                                                       \
    _Pragma("unroll") for (int i = 0; i < 4; ++i)                            \
      gload_lds16(A + (size_t)(m0 + ar[i]) * 1024 + (kt) + aso[i],           \
                  (char*)Af[buf] + ua[i] * 16);                              \
    gload_lds16(Wz + (size_t)(n0 + brow0) * 1024 + (kt) + bk0,               \
                (char*)Bs[buf] + (w * 2 + 0) * 1024 + l * 16);               \
    gload_lds16(Wz + (size_t)(n0 + brow1) * 1024 + (kt) + bk1,               \
                (char*)Bs[buf] + (w * 2 + 1) * 1024 + l * 16);               \
  } while (0)

  STAGE_QKV(0, 0);
  STAGE_QKV(1, 32);

  for (int t = 0; t < 32; ++t) {
    if (t < 30) {
      STAGE_QKV((t + 2) % 3, (t + 2) * 32);
      // outstanding: tile t+1 (6) + tile t+2 (6); vmcnt(12) -> tile t landed
      asm volatile("s_waitcnt vmcnt(12)" ::: "memory");
    } else if (t == 30) {
      asm volatile("s_waitcnt vmcnt(6)" ::: "memory");   // tile 30 landed
    } else {
      asm volatile("s_waitcnt vmcnt(0)" ::: "memory");   // tile 31 landed
    }
    __builtin_amdgcn_s_barrier();
    __builtin_amdgcn_sched_barrier(0);

    const int cur = t % 3;
    bf16x8 af[4], bfr[4];
#pragma unroll
    for (int mt = 0; mt < 4; ++mt) {
      int row = wm + mt * 16 + c16;     // (row>>1)&3 == rsw
      int base = (ghf << 11) + row * 16;
      int pl = (((g & 1) * 2)     ^ rsw ^ ghf) << 2;
      int ph = (((g & 1) * 2 + 1) ^ rsw ^ ghf) << 2;
      f32x4 lo = *(const f32x4*)&Af[cur][base + pl];
      f32x4 hi = *(const f32x4*)&Af[cur][base + ph];
      bf16x8 h;
#pragma unroll
      for (int j = 0; j < 4; ++j) { h[j] = (bf16)lo[j]; h[4 + j] = (bf16)hi[j]; }
      af[mt] = h;
    }
#pragma unroll
    for (int nt = 0; nt < 4; ++nt)
      bfr[nt] = *(const bf16x8*)&Bs[cur][(wn + nt * 16 + c16) * 32 + ((g ^ rsw) * 8)];
#pragma unroll
    for (int mt = 0; mt < 4; ++mt)
#pragma unroll
      for (int nt = 0; nt < 4; ++nt)
        acc[mt][nt] = mfma16(af[mt], bfr[nt], acc[mt][nt]);

    __builtin_amdgcn_sched_barrier(0);
    __builtin_amdgcn_s_barrier();   // all waves done reading buf t%3 before
                                    // step t+1 stages (t+3)%3 == t%3
  }
#undef STAGE_QKV

  if (z < 2) {
    bf16* Cout = (z == 0) ? outQ : outK;
#pragma unroll
    for (int mt = 0; mt < 4; ++mt)
#pragma unroll
      for (int nt = 0; nt < 4; ++nt) {
        int n = n0 + wn + nt * 16 + c16;
        float bb = bia[n];
#pragma unroll
        for (int r = 0; r < 4; ++r) {
          int m = m0 + wm + mt * 16 + g * 4 + r;
          Cout[(size_t)m * 1024 + n] = (bf16)((acc[mt][nt][r] + bb) * scale);
        }
      }
  } else {
    // V: write transposed -> Vt[(b*16+h)*64 + dk][s], 4 consecutive s per lane
#pragma unroll
    for (int mt = 0; mt < 4; ++mt)
#pragma unroll
      for (int nt = 0; nt < 4; ++nt) {
        int n = n0 + wn + nt * 16 + c16;       // h*64 + dk
        float bb = bia[n];
        int m = m0 + wm + mt * 16 + g * 4;     // b*2048 + s (4-aligned)
        int b = m >> 11, s = m & 2047;
        bf16x4 v;
#pragma unroll
        for (int r = 0; r < 4; ++r) v[r] = (bf16)(acc[mt][nt][r] + bb);
        *(bf16x4*)&Vt[((size_t)(b * 16 + (n >> 6)) * 64 + (n & 63)) * 2048 + s] = v;
      }
  }
}

// ---------------------------------------------------------------------------
// Kernel 3: flash attention, R8 2-stage S-pipeline. Block = (b,h,128 q-rows);
// 4 waves x 32 q-rows. KVBLK=64, quad-buffered LDS, 1 barrier/tile,
// prefetch depth 2. K/V tiles stored [2 half][64 r][32 el] (64B rows,
// chunk ^= (r>>1)&3) -> conflict-free bank pattern.
// ---------------------------------------------------------------------------
__global__ __launch_bounds__(256, 2) void flash_kernel(
    const bf16* __restrict__ Qp, const bf16* __restrict__ Kp,
    const bf16* __restrict__ Vt, bf16* __restrict__ AO) {
  __shared__ __align__(16) bf16 Ks[4][64 * 64];
  __shared__ __align__(16) bf16 Vs[4][64 * 64];

  int orig = blockIdx.x;
  int wg = (orig & 7) * 64 + (orig >> 3);   // XCD-chunked, bijective (512 % 8 == 0)
  int bh = wg >> 4, qb = wg & 15;
  int b = bh >> 4, h = bh & 15;
  int tid = threadIdx.x, w = tid >> 6, l = tid & 63;
  int lo5 = l & 31, g = l >> 5;
  int q0 = qb * 128 + w * 32;

  // Q as B-fragments: qf[kt] = Q[q0+lo5][kt*16 + g*8 + j]
  const bf16* qptr = Qp + (size_t)(b * 2048 + q0 + lo5) * 1024 + h * 64 + g * 8;
  bf16x8 qf0 = *(const bf16x8*)(qptr + 0);
  bf16x8 qf1 = *(const bf16x8*)(qptr + 16);
  bf16x8 qf2 = *(const bf16x8*)(qptr + 32);
  bf16x8 qf3 = *(const bf16x8*)(qptr + 48);

  const bf16* kbase = Kp + (size_t)(b * 2048) * 1024 + h * 64;
  const bf16* vbase = Vt + (size_t)bh * 64 * 2048;

  // staging: 512 16B-units/tile; unit u: half=u>>8, row=(u>>2)&63, ccphys=u&3,
  // logical chunk cc = ccphys ^ ((row>>1)&3). Thread stages unit un (half 0)
  // and un+256 (half 1) of both K and V -> same row/cc, k-offsets +0/+32.
  int un = w * 64 + l;                 // 0..255
  int ur = un >> 2;                    // row 0..63
  int uc = (un & 3) ^ ((ur >> 1) & 3); // logical chunk 0..3
  int ub = un * 8;                     // dest elem offset (half 0)
  int swr = (lo5 >> 1) & 3;            // read-side swizzle

  // STAGE issue order: K,K,V,V (vmcnt counting relies on this)
#define STAGE(buf, s0)                                                          \
  do {                                                                          \
    gload_lds16(kbase + (size_t)((s0) + ur) * 1024 + uc * 8,                    \
                (bf16*)Ks[buf] + ub);                                           \
    gload_lds16(kbase + (size_t)((s0) + ur) * 1024 + 32 + uc * 8,               \
                (bf16*)Ks[buf] + 2048 + ub);                                    \
    gload_lds16(vbase + (size_t)ur * 2048 + (s0) + uc * 8,                      \
                (bf16*)Vs[buf] + ub);                                           \
    gload_lds16(vbase + (size_t)ur * 2048 + (s0) + 32 + uc * 8,                 \
                (bf16*)Vs[buf] + 2048 + ub);                                    \
  } while (0)

  // elem = half*2048 + row*32 + ((cc ^ swr)*8); half = kt>>1, cc = (2kt+g)&3
#define LDSK(cp, nt, kt)                                                        \
  (*(const bf16x8*)&cp[(((kt) >> 1) << 11) + (((nt)*32 + lo5) << 5) +           \
                       (((((kt)*2 + g) & 3) ^ swr) << 3)])
#define LDSV(cp, dt, st)                                                        \
  (*(const bf16x8*)&cp[(((st) >> 1) << 11) + (((dt)*32 + lo5) << 5) +           \
                       (((((st)*2 + g) & 3) ^ swr) << 3)])

#define QK(d0, d1, kc)                                                          \
  do {                                                                          \
    __builtin_amdgcn_s_setprio(1);                                              \
    d0 = z16; d1 = z16;                                                         \
    d0 = mfma32(LDSK(kc, 0, 0), qf0, d0);                                       \
    d0 = mfma32(LDSK(kc, 0, 1), qf1, d0);                                       \
    d0 = mfma32(LDSK(kc, 0, 2), qf2, d0);                                       \
    d0 = mfma32(LDSK(kc, 0, 3), qf3, d0);                                       \
    d1 = mfma32(LDSK(kc, 1, 0), qf0, d1);                                       \
    d1 = mfma32(LDSK(kc, 1, 1), qf1, d1);                                       \
    d1 = mfma32(LDSK(kc, 1, 2), qf2, d1);                                       \
    d1 = mfma32(LDSK(kc, 1, 3), qf3, d1);                                       \
    __builtin_amdgcn_s_setprio(0);                                              \
  } while (0)

#define SOFTMAX(sv, sw)                                                         \
  do {                                                                          \
    float p[16];                                                                \
    _Pragma("unroll") for (int r = 0; r < 16; ++r) p[r] = fexp2(sv[r]);         \
    ps0 += p[0] + p[4] + p[8] + p[12];                                          \
    ps1 += p[1] + p[5] + p[9] + p[13];                                          \
    ps2 += p[2] + p[6] + p[10] + p[14];                                         \
    ps3 += p[3] + p[7] + p[11] + p[15];                                         \
    unsigned pw0 = pack2(p[0], p[1]), pw1 = pack2(p[2], p[3]);                  \
    unsigned pw2 = pack2(p[4], p[5]), pw3 = pack2(p[6], p[7]);                  \
    unsigned pw4 = pack2(p[8], p[9]), pw5 = pack2(p[10], p[11]);                \
    unsigned pw6 = pack2(p[12], p[13]), pw7 = pack2(p[14], p[15]);              \
    uint2v a02 = __builtin_amdgcn_permlane32_swap(pw0, pw2, false, false);      \
    uint2v a13 = __builtin_amdgcn_permlane32_swap(pw1, pw3, false, false);      \
    uint2v a46 = __builtin_amdgcn_permlane32_swap(pw4, pw6, false, false);      \
    uint2v a57 = __builtin_amdgcn_permlane32_swap(pw5, pw7, false, false);      \
    pa0 = mk8(a02.x, a13.x, a02.y, a13.y);                                      \
    pa1 = mk8(a46.x, a57.x, a46.y, a57.y);                                      \
    _Pragma("unroll") for (int r = 0; r < 16; ++r) p[r] = fexp2(sw[r]);         \
    ps0 += p[0] + p[4] + p[8] + p[12];                                          \
    ps1 += p[1] + p[5] + p[9] + p[13];                                          \
    ps2 += p[2] + p[6] + p[10] + p[14];                                         \
    ps3 += p[3] + p[7] + p[11] + p[15];                                         \
    pw0 = pack2(p[0], p[1]); pw1 = pack2(p[2], p[3]);                           \
    pw2 = pack2(p[4], p[5]); pw3 = pack2(p[6], p[7]);                           \
    pw4 = pack2(p[8], p[9]); pw5 = pack2(p[10], p[11]);                         \
    pw6 = pack2(p[12], p[13]); pw7 = pack2(p[14], p[15]);                       \
    a02 = __builtin_amdgcn_permlane32_swap(pw0, pw2, false, false);             \
    a13 = __builtin_amdgcn_permlane32_swap(pw1, pw3, false, false);             \
    a46 = __builtin_amdgcn_permlane32_swap(pw4, pw6, false, false);             \
    a57 = __builtin_amdgcn_permlane32_swap(pw5, pw7, false, false);             \
    pb0 = mk8(a02.x, a13.x, a02.y, a13.y);                                      \
    pb1 = mk8(a46.x, a57.x, a46.y, a57.y);                                      \
  } while (0)

#define PV(vc)                                                                  \
  do {                                                                          \
    __builtin_amdgcn_s_setprio(1);                                              \
    o0 = mfma32(pa0, LDSV(vc, 0, 0), o0);                                       \
    o1 = mfma32(pa0, LDSV(vc, 1, 0), o1);                                       \
    o0 = mfma32(pa1, LDSV(vc, 0, 1), o0);                                       \
    o1 = mfma32(pa1, LDSV(vc, 1, 1), o1);                                       \
    o0 = mfma32(pb0, LDSV(vc, 0, 2), o0);                                       \
    o1 = mfma32(pb0, LDSV(vc, 1, 2), o1);                                       \
    o0 = mfma32(pb1, LDSV(vc, 0, 3), o0);                                       \
    o1 = mfma32(pb1, LDSV(vc, 1, 3), o1);                                       \
    __builtin_amdgcn_s_setprio(0);                                              \
  } while (0)

  const f32x16 z16 = {};
  f32x16 o0 = z16, o1 = z16;
  f32x16 sA0, sA1, sB0, sB1;
  bf16x8 pa0, pa1, pb0, pb1;
  float ps0 = 0.f, ps1 = 0.f, ps2 = 0.f, ps3 = 0.f;

  STAGE(0, 0);
  STAGE(1, 64);
  // vmcnt(6): of 8 outstanding (K0,K0,V0,V0,K1,K1,V1,V1), newest 6 remain
  // -> K0 landed. Barrier makes all waves' K0 parts visible.
  asm volatile("s_waitcnt vmcnt(6)" ::: "memory");
  __builtin_amdgcn_s_barrier();
  __builtin_amdgcn_sched_barrier(0);
  QK(sA0, sA1, Ks[0]);  // tile 0 -> state A

  for (int t = 0; t < 32; t += 2) {
    // ---- step t (even): current = A(tile t), next = B(tile t+1) ----
    if (t < 30) {
      STAGE((t + 2) & 3, (t + 2) * 64);
      // outstanding: V(t)x2 + tile(t+1)x4 + tile(t+2)x4; vmcnt(6) leaves
      // [V(t+1)x2, tile(t+2)x4] -> V(t) and K(t+1) landed.
      asm volatile("s_waitcnt vmcnt(6)" ::: "memory");
    } else {
      asm volatile("s_waitcnt vmcnt(2)" ::: "memory");  // V30 + K31 landed
    }
    __builtin_amdgcn_s_barrier();
    __builtin_amdgcn_sched_barrier(0);
    QK(sB0, sB1, Ks[(t + 1) & 3]);   // tile t+1 (matrix pipe, independent)
    SOFTMAX(sA0, sA1);               // tile t (VALU) - overlaps QK above
    PV(Vs[t & 3]);                   // tile t

    // ---- step t+1 (odd): current = B(tile t+1), next = A(tile t+2) ----
    if (t < 29) {
      STAGE((t + 3) & 3, (t + 3) * 64);
      asm volatile("s_waitcnt vmcnt(6)" ::: "memory");
    } else {
      asm volatile("s_waitcnt vmcnt(0)" ::: "memory");  // V31 landed
    }
    __builtin_amdgcn_s_barrier();
    __builtin_amdgcn_sched_barrier(0);
    if (t < 30) QK(sA0, sA1, Ks[(t + 2) & 3]);  // tile t+2
    SOFTMAX(sB0, sB1);
    PV(Vs[(t + 1) & 3]);
  }
#undef STAGE
#undef LDSK
#undef LDSV
#undef QK
#undef SOFTMAX
#undef PV

  // tot on lane l = softmax denominator for q = q0 + (l&31)
  float plsum = (ps0 + ps1) + (ps2 + ps3);
  float tot = plsum + __shfl_xor(plsum, 32);

#pragma unroll
  for (int r = 0; r < 16; ++r) {
    int qr = (r & 3) + 8 * (r >> 2) + 4 * g;        // output row of o0[r]/o1[r]
    float inv = 1.0f / __shfl(tot, qr);             // row qr's denominator
    bf16* op = AO + (size_t)(b * 2048 + q0 + qr) * 1024 + h * 64 + lo5;
    op[0]  = (bf16)(o0[r] * inv);
    op[32] = (bf16)(o1[r] * inv);
  }
}

// ---------------------------------------------------------------------------
// Kernel 4: output projection, 64x128 tile (512 blocks = 2/CU), m97 structure,
// swizzled LDS. fp32 out + bias.
// ---------------------------------------------------------------------------
__global__ __launch_bounds__(256) void gemm_o(
    const bf16* __restrict__ A, const bf16* __restrict__ Wt3,
    const float* __restrict__ bo, float* __restrict__ C) {
  __shared__ bf16 As[2][64 * 32];
  __shared__ bf16 Bs[2][128 * 32];
  int m0 = blockIdx.x * 64, n0 = blockIdx.y * 128;
  int tid = threadIdx.x, w = tid >> 6, l = tid & 63;
  int wm = (w >> 1) * 32, wn = (w & 1) * 64;
  int c16 = l & 15, g = l >> 4;
  int rsw = (c16 >> 1) & 3;

  // A staging: 1 chunk/lane. row = tid>>2, phys chunk = tid&3
  int arow = tid >> 2, akc = tid & 3;
  int asrc = (akc ^ ((arow >> 1) & 3)) * 8;
  // B staging: 2 chunks/lane
  int brow0 = (w * 2 + 0) * 16 + (l >> 2);
  int brow1 = (w * 2 + 1) * 16 + (l >> 2);
  int bk0 = ((l & 3) ^ ((brow0 >> 1) & 3)) * 8;
  int bk1 = ((l & 3) ^ ((brow1 >> 1) & 3)) * 8;

  f32x4 acc[2][4] = {};

#define STAGE_O(buf, kt)                                                     \
  do {                                                                       \
    gload_lds16(A + (size_t)(m0 + arow) * 1024 + (kt) + asrc,                \
                (char*)As[buf] + tid * 16);                                  \
    gload_lds16(Wt3 + (size_t)(n0 + brow0) * 1024 + (kt) + bk0,              \
                (char*)Bs[buf] + (w * 2 + 0) * 1024 + l * 16);               \
    gload_lds16(Wt3 + (size_t)(n0 + brow1) * 1024 + (kt) + bk1,              \
                (char*)Bs[buf] + (w * 2 + 1) * 1024 + l * 16);               \
  } while (0)

  STAGE_O(0, 0);
  __syncthreads();

  int cur = 0;
  for (int kt = 0; kt < 1024; kt += 32) {
    if (kt < 992) STAGE_O(cur ^ 1, kt + 32);
    bf16x8 af[2], bfr[4];
#pragma unroll
    for (int mt = 0; mt < 2; ++mt)
      af[mt] = *(const bf16x8*)&As[cur][(wm + mt * 16 + c16) * 32 + ((g ^ rsw) * 8)];
#pragma unroll
    for (int nt = 0; nt < 4; ++nt)
      bfr[nt] = *(const bf16x8*)&Bs[cur][(wn + nt * 16 + c16) * 32 + ((g ^ rsw) * 8)];
#pragma unroll
    for (int mt = 0; mt < 2; ++mt)
#pragma unroll
      for (int nt = 0; nt < 4; ++nt)
        acc[mt][nt] = mfma16(af[mt], bfr[nt], acc[mt][nt]);
    __syncthreads();  // drains vmcnt -> next buffer staged
    cur ^= 1;
  }
#undef STAGE_O

#pragma unroll
  for (int mt = 0; mt < 2; ++mt)
#pragma unroll
    for (int nt = 0; nt < 4; ++nt) {
      int n = n0 + wn + nt * 16 + c16;
      float bb = bo[n];
#pragma unroll
      for (int r = 0; r < 4; ++r) {
        int m = m0 + wm + mt * 16 + g * 4 + r;
        C[(size_t)m * 1024 + n] = acc[mt][nt][r] + bb;
      }
    }
}

// ---------------------------------------------------------------------------
extern "C" void kernel_launch(void* const* d_in, const int* in_sizes, int n_in,
                              void* d_out, int out_size, void* d_ws, size_t ws_size,
                              hipStream_t stream) {
  const float* query = (const float*)d_in[0];
  const float* key_  = (const float*)d_in[1];
  const float* value = (const float*)d_in[2];
  const float* Wq = (const float*)d_in[3];
  const float* bq = (const float*)d_in[4];
  const float* Wk = (const float*)d_in[5];
  const float* bk = (const float*)d_in[6];
  const float* Wv = (const float*)d_in[7];
  const float* bv = (const float*)d_in[8];
  const float* Wo = (const float*)d_in[9];
  const float* bo = (const float*)d_in[10];
  float* out = (float*)d_out;

  char* ws = (char*)d_ws;
  const size_t MB = 1024 * 1024;
  bf16* Wt  = (bf16*)(ws);              // 4 x [1024][1024] bf16 = 8 MB
  bf16* Qp  = (bf16*)(ws + 8 * MB);     // [4096][1024] bf16 (pre-scaled)
  bf16* Kp  = (bf16*)(ws + 16 * MB);    // [4096][1024]
  bf16* Vt  = (bf16*)(ws + 24 * MB);    // [32][64][2048]
  bf16* AO  = (bf16*)(ws + 32 * MB);    // attn out [4096][1024]

  wt_kernel<<<dim3(256, 4), dim3(256), 0, stream>>>(Wq, Wk, Wv, Wo, Wt);
  gemm_qkv<<<dim3(32, 8, 3), dim3(256), 0, stream>>>(query, key_, value, Wt,
                                                     bq, bk, bv, Qp, Kp, Vt);
  flash_kernel<<<dim3(512), dim3(256), 0, stream>>>(Qp, Kp, Vt, AO);
  gemm_o<<<dim3(64, 8), dim3(256), 0, stream>>>(AO, Wt + (size_t)3 * 1024 * 1024, bo, out);
}

// Round 13
// 130.199 us; speedup vs baseline: 1.0854x; 1.0854x over previous
//
#include <hip/hip_runtime.h>
#include <hip/hip_bf16.h>
#include <stdint.h>
#include <stddef.h>

// MHA fwd: B=2 S=2048 D=1024 H=16 DK=64.
// wt (W->Wt bf16) -> gemm_qkv (fp32-A via global_load_lds, 2-phase m97
// structure, 512-THREAD blocks: 8 waves on a 128x128 tile -> 24 waves/CU) ->
// flash (R8 2-stage S-pipeline + 64B-row conflict-free K/V layout) ->
// gemm_o (64x128).
//
// R13: R12's mod-3 counted-vmcnt regressed (2nd barrier + 2 blocks/CU).
// Forensics: qkv's 3.15M conflicts are LAYOUT-INVARIANT (bit-identical
// across R6/R11/R12 layouts) = 1 cy per f32x4 A-read floor - inert, stop
// chasing. Real limiter: occupancy 23% (3 waves/SIMD) cannot cover the
// 2-phase barrier drain. Fix: same tile, same LDS, same structure, but
// 512-thread blocks (8 waves, 2x4 split, 64x32/wave) -> 24 waves/CU
// (6/SIMD), doubling barrier-drain cover. Everything else = R11 (best).

typedef __bf16 bf16;
typedef __attribute__((ext_vector_type(4))) bf16 bf16x4;
typedef __attribute__((ext_vector_type(8))) bf16 bf16x8;
typedef __attribute__((ext_vector_type(4))) float f32x4;
typedef __attribute__((ext_vector_type(16))) float f32x16;
typedef __attribute__((ext_vector_type(2))) unsigned int uint2v;

#define DEVINL static __device__ __forceinline__

DEVINL void gload_lds16(const void* g, void* l) {
  __builtin_amdgcn_global_load_lds(
      (const __attribute__((address_space(1))) void*)g,
      (__attribute__((address_space(3))) void*)l, 16, 0, 0);
}

DEVINL f32x4 mfma16(bf16x8 a, bf16x8 b, f32x4 c) {
  return __builtin_amdgcn_mfma_f32_16x16x32_bf16(a, b, c, 0, 0, 0);
}
DEVINL f32x16 mfma32(bf16x8 a, bf16x8 b, f32x16 c) {
  return __builtin_amdgcn_mfma_f32_32x32x16_bf16(a, b, c, 0, 0, 0);
}
// v_exp_f32 computes 2^x; log2(e) is folded into the Q pre-scale.
DEVINL float fexp2(float x) {
  float r;
  asm("v_exp_f32 %0, %1" : "=v"(r) : "v"(x));
  return r;
}
// RNE f32->bf16 pair pack via compiler casts (m240: don't hand-write cvt_pk).
DEVINL unsigned pack2(float lo, float hi) {
  union { bf16 h[2]; unsigned u; } t;
  t.h[0] = (bf16)lo; t.h[1] = (bf16)hi;
  return t.u;
}
DEVINL bf16x8 mk8(unsigned a, unsigned b, unsigned c, unsigned d) {
  union { unsigned u[4]; bf16x8 v; } t;
  t.u[0] = a; t.u[1] = b; t.u[2] = c; t.u[3] = d;
  return t.v;
}

// ---------------------------------------------------------------------------
// Kernel 1: weight transpose+convert. W[k][n] fp32 -> Wt[t][n][k] bf16
// ---------------------------------------------------------------------------
__global__ __launch_bounds__(256) void wt_kernel(
    const float* __restrict__ w0, const float* __restrict__ w1,
    const float* __restrict__ w2, const float* __restrict__ w3,
    bf16* __restrict__ out) {
  __shared__ float tile[64 * 65];
  int t = blockIdx.y;
  const float* w = (t == 0) ? w0 : (t == 1) ? w1 : (t == 2) ? w2 : w3;
  bf16* o = out + (size_t)t * 1024 * 1024;
  int tb = blockIdx.x;
  int k0 = (tb >> 4) * 64, n0 = (tb & 15) * 64;
  int c = threadIdx.x & 63, r0 = threadIdx.x >> 6;
  for (int r = r0; r < 64; r += 4)
    tile[r * 65 + c] = w[(size_t)(k0 + r) * 1024 + n0 + c];
  __syncthreads();
  for (int r = r0; r < 64; r += 4)
    o[(size_t)(n0 + r) * 1024 + k0 + c] = (bf16)tile[c * 65 + r];
}

// ---------------------------------------------------------------------------
// Kernel 2: QKV projection GEMM, 512 threads (8 waves, 2x4 split, 64x32 per
// wave). A = fp32 staged via global_load_lds into [hf][128 r][16 f32] tiles
// (chunk ^= (r>>1)&3); in-reg cvt to bf16 after ds_read. B = bf16 Wt.
// 2-phase m97 structure (STAGE t+1; compute t; one __syncthreads).
// Q scaled by 0.125*log2e in epilogue -> Qp; K -> Kp; V transposed -> Vt.
// ---------------------------------------------------------------------------
__global__ __launch_bounds__(512) void gemm_qkv(
    const float* __restrict__ Aq, const float* __restrict__ Ak,
    const float* __restrict__ Av, const bf16* __restrict__ Wt,
    const float* __restrict__ bq, const float* __restrict__ bk,
    const float* __restrict__ bv,
    bf16* __restrict__ outQ, bf16* __restrict__ outK, bf16* __restrict__ Vt) {
  int z = blockIdx.z;
  const float* A   = (z == 0) ? Aq : (z == 1) ? Ak : Av;
  const bf16* Wz   = Wt + (size_t)z * 1024 * 1024;
  const float* bia = (z == 0) ? bq : (z == 1) ? bk : bv;
  float scale      = (z == 0) ? 0.18033688011112042f : 1.0f;  // 0.125*log2(e)

  __shared__ float Af[2][4096];       // [hf][128 r][16 f32], 16KB each
  __shared__ bf16  Bs[2][128 * 32];   // 8KB each; total 48KB

  int m0 = blockIdx.x * 128, n0 = blockIdx.y * 128;
  int tid = threadIdx.x, w = tid >> 6, l = tid & 63;
  int wm = (w >> 2) * 64, wn = (w & 3) * 32;   // 2x4 wave grid
  int c16 = l & 15, g = l >> 4;
  int rsw = (c16 >> 1) & 3;           // read-side row swizzle
  int ghf = g >> 1;                   // k-half of this lane group

  // A staging: 1024 16B-units over 512 threads (2 each); unit u: hf=u>>9,
  // r=(u>>2)&127, pc=u&3, logical chunk cc = pc ^ ((r>>1)&3);
  // src floats = kt + hf*16 + cc*4.
  int ua[2], ar[2], aso[2];
#pragma unroll
  for (int i = 0; i < 2; ++i) {
    ua[i] = i * 512 + tid;
    int rr = (ua[i] >> 2) & 127;
    int cc = (ua[i] & 3) ^ ((rr >> 1) & 3);
    ar[i] = rr;
    aso[i] = ((ua[i] >> 9) << 4) + cc * 4;
  }
  // B staging: 512 16B-units, 1/thread; unit u: row=u>>2, pc=u&3,
  // src k-chunk = (pc ^ ((row>>1)&3))*8 bf16.
  int brow = tid >> 2;
  int bko  = ((tid & 3) ^ ((brow >> 1) & 3)) * 8;

  f32x4 acc[4][2] = {};

#define STAGE_QKV(buf, kt)                                                   \
  do {                                                                       \
    _Pragma("unroll") for (int i = 0; i < 2; ++i)                            \
      gload_lds16(A + (size_t)(m0 + ar[i]) * 1024 + (kt) + aso[i],           \
                  (char*)Af[buf] + ua[i] * 16);                              \
    gload_lds16(Wz + (size_t)(n0 + brow) * 1024 + (kt) + bko,                \
                (char*)Bs[buf] + tid * 16);                                  \
  } while (0)

  STAGE_QKV(0, 0);
  __syncthreads();

  int cur = 0;
  for (int kt = 0; kt < 1024; kt += 32) {
    if (kt < 992) STAGE_QKV(cur ^ 1, kt + 32);
    bf16x8 af[4], bfr[2];
#pragma unroll
    for (int mt = 0; mt < 4; ++mt) {
      int row = wm + mt * 16 + c16;     // (row>>1)&3 == rsw
      int base = (ghf << 11) + row * 16;
      f32x4 lo = *(const f32x4*)&Af[cur][base + ((((g & 1) * 2)     ^ rsw) << 2)];
      f32x4 hi = *(const f32x4*)&Af[cur][base + ((((g & 1) * 2 + 1) ^ rsw) << 2)];
      bf16x8 h;
#pragma unroll
      for (int j = 0; j < 4; ++j) { h[j] = (bf16)lo[j]; h[4 + j] = (bf16)hi[j]; }
      af[mt] = h;
    }
#pragma unroll
    for (int nt = 0; nt < 2; ++nt)
      bfr[nt] = *(const bf16x8*)&Bs[cur][(wn + nt * 16 + c16) * 32 + ((g ^ rsw) * 8)];
#pragma unroll
    for (int mt = 0; mt < 4; ++mt)
#pragma unroll
      for (int nt = 0; nt < 2; ++nt)
        acc[mt][nt] = mfma16(af[mt], bfr[nt], acc[mt][nt]);
    __syncthreads();  // drains vmcnt -> next buffer staged
    cur ^= 1;
  }
#undef STAGE_QKV

  if (z < 2) {
    bf16* Cout = (z == 0) ? outQ : outK;
#pragma unroll
    for (int mt = 0; mt < 4; ++mt)
#pragma unroll
      for (int nt = 0; nt < 2; ++nt) {
        int n = n0 + wn + nt * 16 + c16;
        float bb = bia[n];
#pragma unroll
        for (int r = 0; r < 4; ++r) {
          int m = m0 + wm + mt * 16 + g * 4 + r;
          Cout[(size_t)m * 1024 + n] = (bf16)((acc[mt][nt][r] + bb) * scale);
        }
      }
  } else {
    // V: write transposed -> Vt[(b*16+h)*64 + dk][s], 4 consecutive s per lane
#pragma unroll
    for (int mt = 0; mt < 4; ++mt)
#pragma unroll
      for (int nt = 0; nt < 2; ++nt) {
        int n = n0 + wn + nt * 16 + c16;       // h*64 + dk
        float bb = bia[n];
        int m = m0 + wm + mt * 16 + g * 4;     // b*2048 + s (4-aligned)
        int b = m >> 11, s = m & 2047;
        bf16x4 v;
#pragma unroll
        for (int r = 0; r < 4; ++r) v[r] = (bf16)(acc[mt][nt][r] + bb);
        *(bf16x4*)&Vt[((size_t)(b * 16 + (n >> 6)) * 64 + (n & 63)) * 2048 + s] = v;
      }
  }
}

// ---------------------------------------------------------------------------
// Kernel 3: flash attention, R8 2-stage S-pipeline. Block = (b,h,128 q-rows);
// 4 waves x 32 q-rows. KVBLK=64, quad-buffered LDS, 1 barrier/tile,
// prefetch depth 2. K/V tiles stored [2 half][64 r][32 el] (64B rows,
// chunk ^= (r>>1)&3) -> conflict-free bank pattern.
// ---------------------------------------------------------------------------
__global__ __launch_bounds__(256, 2) void flash_kernel(
    const bf16* __restrict__ Qp, const bf16* __restrict__ Kp,
    const bf16* __restrict__ Vt, bf16* __restrict__ AO) {
  __shared__ __align__(16) bf16 Ks[4][64 * 64];
  __shared__ __align__(16) bf16 Vs[4][64 * 64];

  int orig = blockIdx.x;
  int wg = (orig & 7) * 64 + (orig >> 3);   // XCD-chunked, bijective (512 % 8 == 0)
  int bh = wg >> 4, qb = wg & 15;
  int b = bh >> 4, h = bh & 15;
  int tid = threadIdx.x, w = tid >> 6, l = tid & 63;
  int lo5 = l & 31, g = l >> 5;
  int q0 = qb * 128 + w * 32;

  // Q as B-fragments: qf[kt] = Q[q0+lo5][kt*16 + g*8 + j]
  const bf16* qptr = Qp + (size_t)(b * 2048 + q0 + lo5) * 1024 + h * 64 + g * 8;
  bf16x8 qf0 = *(const bf16x8*)(qptr + 0);
  bf16x8 qf1 = *(const bf16x8*)(qptr + 16);
  bf16x8 qf2 = *(const bf16x8*)(qptr + 32);
  bf16x8 qf3 = *(const bf16x8*)(qptr + 48);

  const bf16* kbase = Kp + (size_t)(b * 2048) * 1024 + h * 64;
  const bf16* vbase = Vt + (size_t)bh * 64 * 2048;

  // staging: 512 16B-units/tile; unit u: half=u>>8, row=(u>>2)&63, ccphys=u&3,
  // logical chunk cc = ccphys ^ ((row>>1)&3). Thread stages unit un (half 0)
  // and un+256 (half 1) of both K and V -> same row/cc, k-offsets +0/+32.
  int un = w * 64 + l;                 // 0..255
  int ur = un >> 2;                    // row 0..63
  int uc = (un & 3) ^ ((ur >> 1) & 3); // logical chunk 0..3
  int ub = un * 8;                     // dest elem offset (half 0)
  int swr = (lo5 >> 1) & 3;            // read-side swizzle

  // STAGE issue order: K,K,V,V (vmcnt counting relies on this)
#define STAGE(buf, s0)                                                          \
  do {                                                                          \
    gload_lds16(kbase + (size_t)((s0) + ur) * 1024 + uc * 8,                    \
                (bf16*)Ks[buf] + ub);                                           \
    gload_lds16(kbase + (size_t)((s0) + ur) * 1024 + 32 + uc * 8,               \
                (bf16*)Ks[buf] + 2048 + ub);                                    \
    gload_lds16(vbase + (size_t)ur * 2048 + (s0) + uc * 8,                      \
                (bf16*)Vs[buf] + ub);                                           \
    gload_lds16(vbase + (size_t)ur * 2048 + (s0) + 32 + uc * 8,                 \
                (bf16*)Vs[buf] + 2048 + ub);                                    \
  } while (0)

  // elem = half*2048 + row*32 + ((cc ^ swr)*8); half = kt>>1, cc = (2kt+g)&3
#define LDSK(cp, nt, kt)                                                        \
  (*(const bf16x8*)&cp[(((kt) >> 1) << 11) + (((nt)*32 + lo5) << 5) +           \
                       (((((kt)*2 + g) & 3) ^ swr) << 3)])
#define LDSV(cp, dt, st)                                                        \
  (*(const bf16x8*)&cp[(((st) >> 1) << 11) + (((dt)*32 + lo5) << 5) +           \
                       (((((st)*2 + g) & 3) ^ swr) << 3)])

#define QK(d0, d1, kc)                                                          \
  do {                                                                          \
    __builtin_amdgcn_s_setprio(1);                                              \
    d0 = z16; d1 = z16;                                                         \
    d0 = mfma32(LDSK(kc, 0, 0), qf0, d0);                                       \
    d0 = mfma32(LDSK(kc, 0, 1), qf1, d0);                                       \
    d0 = mfma32(LDSK(kc, 0, 2), qf2, d0);                                       \
    d0 = mfma32(LDSK(kc, 0, 3), qf3, d0);                                       \
    d1 = mfma32(LDSK(kc, 1, 0), qf0, d1);                                       \
    d1 = mfma32(LDSK(kc, 1, 1), qf1, d1);                                       \
    d1 = mfma32(LDSK(kc, 1, 2), qf2, d1);                                       \
    d1 = mfma32(LDSK(kc, 1, 3), qf3, d1);                                       \
    __builtin_amdgcn_s_setprio(0);                                              \
  } while (0)

#define SOFTMAX(sv, sw)                                                         \
  do {                                                                          \
    float p[16];                                                                \
    _Pragma("unroll") for (int r = 0; r < 16; ++r) p[r] = fexp2(sv[r]);         \
    ps0 += p[0] + p[4] + p[8] + p[12];                                          \
    ps1 += p[1] + p[5] + p[9] + p[13];                                          \
    ps2 += p[2] + p[6] + p[10] + p[14];                                         \
    ps3 += p[3] + p[7] + p[11] + p[15];                                         \
    unsigned pw0 = pack2(p[0], p[1]), pw1 = pack2(p[2], p[3]);                  \
    unsigned pw2 = pack2(p[4], p[5]), pw3 = pack2(p[6], p[7]);                  \
    unsigned pw4 = pack2(p[8], p[9]), pw5 = pack2(p[10], p[11]);                \
    unsigned pw6 = pack2(p[12], p[13]), pw7 = pack2(p[14], p[15]);              \
    uint2v a02 = __builtin_amdgcn_permlane32_swap(pw0, pw2, false, false);      \
    uint2v a13 = __builtin_amdgcn_permlane32_swap(pw1, pw3, false, false);      \
    uint2v a46 = __builtin_amdgcn_permlane32_swap(pw4, pw6, false, false);      \
    uint2v a57 = __builtin_amdgcn_permlane32_swap(pw5, pw7, false, false);      \
    pa0 = mk8(a02.x, a13.x, a02.y, a13.y);                                      \
    pa1 = mk8(a46.x, a57.x, a46.y, a57.y);                                      \
    _Pragma("unroll") for (int r = 0; r < 16; ++r) p[r] = fexp2(sw[r]);         \
    ps0 += p[0] + p[4] + p[8] + p[12];                                          \
    ps1 += p[1] + p[5] + p[9] + p[13];                                          \
    ps2 += p[2] + p[6] + p[10] + p[14];                                         \
    ps3 += p[3] + p[7] + p[11] + p[15];                                         \
    pw0 = pack2(p[0], p[1]); pw1 = pack2(p[2], p[3]);                           \
    pw2 = pack2(p[4], p[5]); pw3 = pack2(p[6], p[7]);                           \
    pw4 = pack2(p[8], p[9]); pw5 = pack2(p[10], p[11]);                         \
    pw6 = pack2(p[12], p[13]); pw7 = pack2(p[14], p[15]);                       \
    a02 = __builtin_amdgcn_permlane32_swap(pw0, pw2, false, false);             \
    a13 = __builtin_amdgcn_permlane32_swap(pw1, pw3, false, false);             \
    a46 = __builtin_amdgcn_permlane32_swap(pw4, pw6, false, false);             \
    a57 = __builtin_amdgcn_permlane32_swap(pw5, pw7, false, false);             \
    pb0 = mk8(a02.x, a13.x, a02.y, a13.y);                                      \
    pb1 = mk8(a46.x, a57.x, a46.y, a57.y);                                      \
  } while (0)

#define PV(vc)                                                                  \
  do {                                                                          \
    __builtin_amdgcn_s_setprio(1);                                              \
    o0 = mfma32(pa0, LDSV(vc, 0, 0), o0);                                       \
    o1 = mfma32(pa0, LDSV(vc, 1, 0), o1);                                       \
    o0 = mfma32(pa1, LDSV(vc, 0, 1), o0);                                       \
    o1 = mfma32(pa1, LDSV(vc, 1, 1), o1);                                       \
    o0 = mfma32(pb0, LDSV(vc, 0, 2), o0);                                       \
    o1 = mfma32(pb0, LDSV(vc, 1, 2), o1);                                       \
    o0 = mfma32(pb1, LDSV(vc, 0, 3), o0);                                       \
    o1 = mfma32(pb1, LDSV(vc, 1, 3), o1);                                       \
    __builtin_amdgcn_s_setprio(0);                                              \
  } while (0)

  const f32x16 z16 = {};
  f32x16 o0 = z16, o1 = z16;
  f32x16 sA0, sA1, sB0, sB1;
  bf16x8 pa0, pa1, pb0, pb1;
  float ps0 = 0.f, ps1 = 0.f, ps2 = 0.f, ps3 = 0.f;

  STAGE(0, 0);
  STAGE(1, 64);
  // vmcnt(6): of 8 outstanding (K0,K0,V0,V0,K1,K1,V1,V1), newest 6 remain
  // -> K0 landed. Barrier makes all waves' K0 parts visible.
  asm volatile("s_waitcnt vmcnt(6)" ::: "memory");
  __builtin_amdgcn_s_barrier();
  __builtin_amdgcn_sched_barrier(0);
  QK(sA0, sA1, Ks[0]);  // tile 0 -> state A

  for (int t = 0; t < 32; t += 2) {
    // ---- step t (even): current = A(tile t), next = B(tile t+1) ----
    if (t < 30) {
      STAGE((t + 2) & 3, (t + 2) * 64);
      // outstanding: V(t)x2 + tile(t+1)x4 + tile(t+2)x4; vmcnt(6) leaves
      // [V(t+1)x2, tile(t+2)x4] -> V(t) and K(t+1) landed.
      asm volatile("s_waitcnt vmcnt(6)" ::: "memory");
    } else {
      asm volatile("s_waitcnt vmcnt(2)" ::: "memory");  // V30 + K31 landed
    }
    __builtin_amdgcn_s_barrier();
    __builtin_amdgcn_sched_barrier(0);
    QK(sB0, sB1, Ks[(t + 1) & 3]);   // tile t+1 (matrix pipe, independent)
    SOFTMAX(sA0, sA1);               // tile t (VALU) - overlaps QK above
    PV(Vs[t & 3]);                   // tile t

    // ---- step t+1 (odd): current = B(tile t+1), next = A(tile t+2) ----
    if (t < 29) {
      STAGE((t + 3) & 3, (t + 3) * 64);
      asm volatile("s_waitcnt vmcnt(6)" ::: "memory");
    } else {
      asm volatile("s_waitcnt vmcnt(0)" ::: "memory");  // V31 landed
    }
    __builtin_amdgcn_s_barrier();
    __builtin_amdgcn_sched_barrier(0);
    if (t < 30) QK(sA0, sA1, Ks[(t + 2) & 3]);  // tile t+2
    SOFTMAX(sB0, sB1);
    PV(Vs[(t + 1) & 3]);
  }
#undef STAGE
#undef LDSK
#undef LDSV
#undef QK
#undef SOFTMAX
#undef PV

  // tot on lane l = softmax denominator for q = q0 + (l&31)
  float plsum = (ps0 + ps1) + (ps2 + ps3);
  float tot = plsum + __shfl_xor(plsum, 32);

#pragma unroll
  for (int r = 0; r < 16; ++r) {
    int qr = (r & 3) + 8 * (r >> 2) + 4 * g;        // output row of o0[r]/o1[r]
    float inv = 1.0f / __shfl(tot, qr);             // row qr's denominator
    bf16* op = AO + (size_t)(b * 2048 + q0 + qr) * 1024 + h * 64 + lo5;
    op[0]  = (bf16)(o0[r] * inv);
    op[32] = (bf16)(o1[r] * inv);
  }
}

// ---------------------------------------------------------------------------
// Kernel 4: output projection, 64x128 tile (512 blocks = 2/CU), m97 structure,
// swizzled LDS. fp32 out + bias.
// ---------------------------------------------------------------------------
__global__ __launch_bounds__(256) void gemm_o(
    const bf16* __restrict__ A, const bf16* __restrict__ Wt3,
    const float* __restrict__ bo, float* __restrict__ C) {
  __shared__ bf16 As[2][64 * 32];
  __shared__ bf16 Bs[2][128 * 32];
  int m0 = blockIdx.x * 64, n0 = blockIdx.y * 128;
  int tid = threadIdx.x, w = tid >> 6, l = tid & 63;
  int wm = (w >> 1) * 32, wn = (w & 1) * 64;
  int c16 = l & 15, g = l >> 4;
  int rsw = (c16 >> 1) & 3;

  // A staging: 1 chunk/lane. row = tid>>2, phys chunk = tid&3
  int arow = tid >> 2, akc = tid & 3;
  int asrc = (akc ^ ((arow >> 1) & 3)) * 8;
  // B staging: 2 chunks/lane
  int brow0 = (w * 2 + 0) * 16 + (l >> 2);
  int brow1 = (w * 2 + 1) * 16 + (l >> 2);
  int bk0 = ((l & 3) ^ ((brow0 >> 1) & 3)) * 8;
  int bk1 = ((l & 3) ^ ((brow1 >> 1) & 3)) * 8;

  f32x4 acc[2][4] = {};

#define STAGE_O(buf, kt)                                                     \
  do {                                                                       \
    gload_lds16(A + (size_t)(m0 + arow) * 1024 + (kt) + asrc,                \
                (char*)As[buf] + tid * 16);                                  \
    gload_lds16(Wt3 + (size_t)(n0 + brow0) * 1024 + (kt) + bk0,              \
                (char*)Bs[buf] + (w * 2 + 0) * 1024 + l * 16);               \
    gload_lds16(Wt3 + (size_t)(n0 + brow1) * 1024 + (kt) + bk1,              \
                (char*)Bs[buf] + (w * 2 + 1) * 1024 + l * 16);               \
  } while (0)

  STAGE_O(0, 0);
  __syncthreads();

  int cur = 0;
  for (int kt = 0; kt < 1024; kt += 32) {
    if (kt < 992) STAGE_O(cur ^ 1, kt + 32);
    bf16x8 af[2], bfr[4];
#pragma unroll
    for (int mt = 0; mt < 2; ++mt)
      af[mt] = *(const bf16x8*)&As[cur][(wm + mt * 16 + c16) * 32 + ((g ^ rsw) * 8)];
#pragma unroll
    for (int nt = 0; nt < 4; ++nt)
      bfr[nt] = *(const bf16x8*)&Bs[cur][(wn + nt * 16 + c16) * 32 + ((g ^ rsw) * 8)];
#pragma unroll
    for (int mt = 0; mt < 2; ++mt)
#pragma unroll
      for (int nt = 0; nt < 4; ++nt)
        acc[mt][nt] = mfma16(af[mt], bfr[nt], acc[mt][nt]);
    __syncthreads();  // drains vmcnt -> next buffer staged
    cur ^= 1;
  }
#undef STAGE_O

#pragma unroll
  for (int mt = 0; mt < 2; ++mt)
#pragma unroll
    for (int nt = 0; nt < 4; ++nt) {
      int n = n0 + wn + nt * 16 + c16;
      float bb = bo[n];
#pragma unroll
      for (int r = 0; r < 4; ++r) {
        int m = m0 + wm + mt * 16 + g * 4 + r;
        C[(size_t)m * 1024 + n] = acc[mt][nt][r] + bb;
      }
    }
}

// ---------------------------------------------------------------------------
extern "C" void kernel_launch(void* const* d_in, const int* in_sizes, int n_in,
                              void* d_out, int out_size, void* d_ws, size_t ws_size,
                              hipStream_t stream) {
  const float* query = (const float*)d_in[0];
  const float* key_  = (const float*)d_in[1];
  const float* value = (const float*)d_in[2];
  const float* Wq = (const float*)d_in[3];
  const float* bq = (const float*)d_in[4];
  const float* Wk = (const float*)d_in[5];
  const float* bk = (const float*)d_in[6];
  const float* Wv = (const float*)d_in[7];
  const float* bv = (const float*)d_in[8];
  const float* Wo = (const float*)d_in[9];
  const float* bo = (const float*)d_in[10];
  float* out = (float*)d_out;

  char* ws = (char*)d_ws;
  const size_t MB = 1024 * 1024;
  bf16* Wt  = (bf16*)(ws);              // 4 x [1024][1024] bf16 = 8 MB
  bf16* Qp  = (bf16*)(ws + 8 * MB);     // [4096][1024] bf16 (pre-scaled)
  bf16* Kp  = (bf16*)(ws + 16 * MB);    // [4096][1024]
  bf16* Vt  = (bf16*)(ws + 24 * MB);    // [32][64][2048]
  bf16* AO  = (bf16*)(ws + 32 * MB);    // attn out [4096][1024]

  wt_kernel<<<dim3(256, 4), dim3(256), 0, stream>>>(Wq, Wk, Wv, Wo, Wt);
  gemm_qkv<<<dim3(32, 8, 3), dim3(512), 0, stream>>>(query, key_, value, Wt,
                                                     bq, bk, bv, Qp, Kp, Vt);
  flash_kernel<<<dim3(512), dim3(256), 0, stream>>>(Qp, Kp, Vt, AO);
  gemm_o<<<dim3(64, 8), dim3(256), 0, stream>>>(AO, Wt + (size_t)3 * 1024 * 1024, bo, out);
}

// Round 14
// 124.757 us; speedup vs baseline: 1.1327x; 1.0436x over previous
//
#include <hip/hip_runtime.h>
#include <hip/hip_bf16.h>
#include <stdint.h>
#include <stddef.h>

// MHA fwd: B=2 S=2048 D=1024 H=16 DK=64.
// wt (W->Wt bf16) -> gemm_qkv (fp32-A via global_load_lds, 2-phase m97
// structure, hf-major 64B-row A tiles) -> flash (R8 2-stage S-pipeline +
// 64B-row conflict-free K/V layout) -> gemm_o (64x128).
//
// R14 (final consolidation): R13's occupancy lever (512-thr qkv, Occ 23->47%)
// was null on MfmaUtil and negative on total (130.2) - qkv is latency-bound
// in a way none of {layout x3, pipelining x2, occupancy x2} moved. Flash
// similarly exhausted (R4/5/6/7/10 null-or-negative around R8 optimum).
// Session best = R8 (124.55) ~= R11 (124.85, + conflict-free flash).
// This is R11 verbatim: the best-measured configuration with the
// mechanistically-correct flash layout.

typedef __bf16 bf16;
typedef __attribute__((ext_vector_type(4))) bf16 bf16x4;
typedef __attribute__((ext_vector_type(8))) bf16 bf16x8;
typedef __attribute__((ext_vector_type(4))) float f32x4;
typedef __attribute__((ext_vector_type(16))) float f32x16;
typedef __attribute__((ext_vector_type(2))) unsigned int uint2v;

#define DEVINL static __device__ __forceinline__

DEVINL void gload_lds16(const void* g, void* l) {
  __builtin_amdgcn_global_load_lds(
      (const __attribute__((address_space(1))) void*)g,
      (__attribute__((address_space(3))) void*)l, 16, 0, 0);
}

DEVINL f32x4 mfma16(bf16x8 a, bf16x8 b, f32x4 c) {
  return __builtin_amdgcn_mfma_f32_16x16x32_bf16(a, b, c, 0, 0, 0);
}
DEVINL f32x16 mfma32(bf16x8 a, bf16x8 b, f32x16 c) {
  return __builtin_amdgcn_mfma_f32_32x32x16_bf16(a, b, c, 0, 0, 0);
}
// v_exp_f32 computes 2^x; log2(e) is folded into the Q pre-scale.
DEVINL float fexp2(float x) {
  float r;
  asm("v_exp_f32 %0, %1" : "=v"(r) : "v"(x));
  return r;
}
// RNE f32->bf16 pair pack via compiler casts (m240: don't hand-write cvt_pk).
DEVINL unsigned pack2(float lo, float hi) {
  union { bf16 h[2]; unsigned u; } t;
  t.h[0] = (bf16)lo; t.h[1] = (bf16)hi;
  return t.u;
}
DEVINL bf16x8 mk8(unsigned a, unsigned b, unsigned c, unsigned d) {
  union { unsigned u[4]; bf16x8 v; } t;
  t.u[0] = a; t.u[1] = b; t.u[2] = c; t.u[3] = d;
  return t.v;
}

// ---------------------------------------------------------------------------
// Kernel 1: weight transpose+convert. W[k][n] fp32 -> Wt[t][n][k] bf16
// ---------------------------------------------------------------------------
__global__ __launch_bounds__(256) void wt_kernel(
    const float* __restrict__ w0, const float* __restrict__ w1,
    const float* __restrict__ w2, const float* __restrict__ w3,
    bf16* __restrict__ out) {
  __shared__ float tile[64 * 65];
  int t = blockIdx.y;
  const float* w = (t == 0) ? w0 : (t == 1) ? w1 : (t == 2) ? w2 : w3;
  bf16* o = out + (size_t)t * 1024 * 1024;
  int tb = blockIdx.x;
  int k0 = (tb >> 4) * 64, n0 = (tb & 15) * 64;
  int c = threadIdx.x & 63, r0 = threadIdx.x >> 6;
  for (int r = r0; r < 64; r += 4)
    tile[r * 65 + c] = w[(size_t)(k0 + r) * 1024 + n0 + c];
  __syncthreads();
  for (int r = r0; r < 64; r += 4)
    o[(size_t)(n0 + r) * 1024 + k0 + c] = (bf16)tile[c * 65 + r];
}

// ---------------------------------------------------------------------------
// Kernel 2: QKV projection GEMM. A = fp32 input staged via global_load_lds
// into a [2 half][128 r][16 f32] (64B-row) tile, chunk ^= (r>>1)&3;
// in-reg cvt to bf16 after ds_read. B = bf16 Wt. 2-phase m97 structure.
// Q scaled by 0.125*log2e in epilogue -> Qp; K -> Kp; V transposed -> Vt.
// ---------------------------------------------------------------------------
__global__ __launch_bounds__(256) void gemm_qkv(
    const float* __restrict__ Aq, const float* __restrict__ Ak,
    const float* __restrict__ Av, const bf16* __restrict__ Wt,
    const float* __restrict__ bq, const float* __restrict__ bk,
    const float* __restrict__ bv,
    bf16* __restrict__ outQ, bf16* __restrict__ outK, bf16* __restrict__ Vt) {
  int z = blockIdx.z;
  const float* A   = (z == 0) ? Aq : (z == 1) ? Ak : Av;
  const bf16* Wz   = Wt + (size_t)z * 1024 * 1024;
  const float* bia = (z == 0) ? bq : (z == 1) ? bk : bv;
  float scale      = (z == 0) ? 0.18033688011112042f : 1.0f;  // 0.125*log2(e)

  __shared__ float Af[2][4096];       // [hf][128 r][16 f32], 16KB each
  __shared__ bf16  Bs[2][128 * 32];   // bf16 B tile, 8KB each

  int m0 = blockIdx.x * 128, n0 = blockIdx.y * 128;
  int tid = threadIdx.x, w = tid >> 6, l = tid & 63;
  int wm = (w >> 1) * 64, wn = (w & 1) * 64;
  int c16 = l & 15, g = l >> 4;
  int rsw = (c16 >> 1) & 3;           // read-side swizzle (A and B)

  // A staging: 1024 16B-units; unit u: hf=u>>9, r=(u>>2)&127, ccphys=u&3,
  // logical chunk cc = (u&3)^((r>>1)&3); src floats = kt + hf*16 + cc*4.
  int ua[4], ar[4], aso[4];
#pragma unroll
  for (int i = 0; i < 4; ++i) {
    ua[i] = (w * 4 + i) * 64 + l;
    int rr = (ua[i] >> 2) & 127;
    int cc = (ua[i] & 3) ^ ((rr >> 1) & 3);
    ar[i] = rr;
    aso[i] = ((ua[i] >> 9) << 4) + cc * 4;
  }
  // B staging: 2 units/thread, pre-swizzled global k-chunk
  int brow0 = (w * 2 + 0) * 16 + (l >> 2);
  int brow1 = (w * 2 + 1) * 16 + (l >> 2);
  int bk0 = ((l & 3) ^ ((brow0 >> 1) & 3)) * 8;
  int bk1 = ((l & 3) ^ ((brow1 >> 1) & 3)) * 8;

  f32x4 acc[4][4] = {};

#define STAGE_QKV(buf, kt)                                                   \
  do {                                                                       \
    _Pragma("unroll") for (int i = 0; i < 4; ++i)                            \
      gload_lds16(A + (size_t)(m0 + ar[i]) * 1024 + (kt) + aso[i],           \
                  (char*)Af[buf] + ua[i] * 16);                              \
    gload_lds16(Wz + (size_t)(n0 + brow0) * 1024 + (kt) + bk0,               \
                (char*)Bs[buf] + (w * 2 + 0) * 1024 + l * 16);               \
    gload_lds16(Wz + (size_t)(n0 + brow1) * 1024 + (kt) + bk1,               \
                (char*)Bs[buf] + (w * 2 + 1) * 1024 + l * 16);               \
  } while (0)

  STAGE_QKV(0, 0);
  __syncthreads();

  int cur = 0;
  for (int kt = 0; kt < 1024; kt += 32) {
    if (kt < 992) STAGE_QKV(cur ^ 1, kt + 32);
    bf16x8 af[4], bfr[4];
#pragma unroll
    for (int mt = 0; mt < 4; ++mt) {
      int row = wm + mt * 16 + c16;     // (row>>1)&3 == rsw
      int base = ((g >> 1) << 11) + row * 16;
      f32x4 lo = *(const f32x4*)&Af[cur][base + ((((g & 1) * 2)     ^ rsw) << 2)];
      f32x4 hi = *(const f32x4*)&Af[cur][base + ((((g & 1) * 2 + 1) ^ rsw) << 2)];
      bf16x8 h;
#pragma unroll
      for (int j = 0; j < 4; ++j) { h[j] = (bf16)lo[j]; h[4 + j] = (bf16)hi[j]; }
      af[mt] = h;
    }
#pragma unroll
    for (int nt = 0; nt < 4; ++nt)
      bfr[nt] = *(const bf16x8*)&Bs[cur][(wn + nt * 16 + c16) * 32 + ((g ^ rsw) * 8)];
#pragma unroll
    for (int mt = 0; mt < 4; ++mt)
#pragma unroll
      for (int nt = 0; nt < 4; ++nt)
        acc[mt][nt] = mfma16(af[mt], bfr[nt], acc[mt][nt]);
    __syncthreads();  // drains vmcnt -> next buffer staged
    cur ^= 1;
  }
#undef STAGE_QKV

  if (z < 2) {
    bf16* Cout = (z == 0) ? outQ : outK;
#pragma unroll
    for (int mt = 0; mt < 4; ++mt)
#pragma unroll
      for (int nt = 0; nt < 4; ++nt) {
        int n = n0 + wn + nt * 16 + c16;
        float bb = bia[n];
#pragma unroll
        for (int r = 0; r < 4; ++r) {
          int m = m0 + wm + mt * 16 + g * 4 + r;
          Cout[(size_t)m * 1024 + n] = (bf16)((acc[mt][nt][r] + bb) * scale);
        }
      }
  } else {
    // V: write transposed -> Vt[(b*16+h)*64 + dk][s], 4 consecutive s per lane
#pragma unroll
    for (int mt = 0; mt < 4; ++mt)
#pragma unroll
      for (int nt = 0; nt < 4; ++nt) {
        int n = n0 + wn + nt * 16 + c16;       // h*64 + dk
        float bb = bia[n];
        int m = m0 + wm + mt * 16 + g * 4;     // b*2048 + s (4-aligned)
        int b = m >> 11, s = m & 2047;
        bf16x4 v;
#pragma unroll
        for (int r = 0; r < 4; ++r) v[r] = (bf16)(acc[mt][nt][r] + bb);
        *(bf16x4*)&Vt[((size_t)(b * 16 + (n >> 6)) * 64 + (n & 63)) * 2048 + s] = v;
      }
  }
}

// ---------------------------------------------------------------------------
// Kernel 3: flash attention, R8 2-stage S-pipeline. Block = (b,h,128 q-rows);
// 4 waves x 32 q-rows. KVBLK=64, quad-buffered LDS, 1 barrier/tile,
// prefetch depth 2. K/V tiles stored [2 half][64 r][32 el] (64B rows,
// chunk ^= (r>>1)&3) -> conflict-free bank pattern.
// ---------------------------------------------------------------------------
__global__ __launch_bounds__(256, 2) void flash_kernel(
    const bf16* __restrict__ Qp, const bf16* __restrict__ Kp,
    const bf16* __restrict__ Vt, bf16* __restrict__ AO) {
  __shared__ __align__(16) bf16 Ks[4][64 * 64];
  __shared__ __align__(16) bf16 Vs[4][64 * 64];

  int orig = blockIdx.x;
  int wg = (orig & 7) * 64 + (orig >> 3);   // XCD-chunked, bijective (512 % 8 == 0)
  int bh = wg >> 4, qb = wg & 15;
  int b = bh >> 4, h = bh & 15;
  int tid = threadIdx.x, w = tid >> 6, l = tid & 63;
  int lo5 = l & 31, g = l >> 5;
  int q0 = qb * 128 + w * 32;

  // Q as B-fragments: qf[kt] = Q[q0+lo5][kt*16 + g*8 + j]
  const bf16* qptr = Qp + (size_t)(b * 2048 + q0 + lo5) * 1024 + h * 64 + g * 8;
  bf16x8 qf0 = *(const bf16x8*)(qptr + 0);
  bf16x8 qf1 = *(const bf16x8*)(qptr + 16);
  bf16x8 qf2 = *(const bf16x8*)(qptr + 32);
  bf16x8 qf3 = *(const bf16x8*)(qptr + 48);

  const bf16* kbase = Kp + (size_t)(b * 2048) * 1024 + h * 64;
  const bf16* vbase = Vt + (size_t)bh * 64 * 2048;

  // staging: 512 16B-units/tile; unit u: half=u>>8, row=(u>>2)&63, ccphys=u&3,
  // logical chunk cc = ccphys ^ ((row>>1)&3). Thread stages unit un (half 0)
  // and un+256 (half 1) of both K and V -> same row/cc, k-offsets +0/+32.
  int un = w * 64 + l;                 // 0..255
  int ur = un >> 2;                    // row 0..63
  int uc = (un & 3) ^ ((ur >> 1) & 3); // logical chunk 0..3
  int ub = un * 8;                     // dest elem offset (half 0)
  int swr = (lo5 >> 1) & 3;            // read-side swizzle

  // STAGE issue order: K,K,V,V (vmcnt counting relies on this)
#define STAGE(buf, s0)                                                          \
  do {                                                                          \
    gload_lds16(kbase + (size_t)((s0) + ur) * 1024 + uc * 8,                    \
                (bf16*)Ks[buf] + ub);                                           \
    gload_lds16(kbase + (size_t)((s0) + ur) * 1024 + 32 + uc * 8,               \
                (bf16*)Ks[buf] + 2048 + ub);                                    \
    gload_lds16(vbase + (size_t)ur * 2048 + (s0) + uc * 8,                      \
                (bf16*)Vs[buf] + ub);                                           \
    gload_lds16(vbase + (size_t)ur * 2048 + (s0) + 32 + uc * 8,                 \
                (bf16*)Vs[buf] + 2048 + ub);                                    \
  } while (0)

  // elem = half*2048 + row*32 + ((cc ^ swr)*8); half = kt>>1, cc = (2kt+g)&3
#define LDSK(cp, nt, kt)                                                        \
  (*(const bf16x8*)&cp[(((kt) >> 1) << 11) + (((nt)*32 + lo5) << 5) +           \
                       (((((kt)*2 + g) & 3) ^ swr) << 3)])
#define LDSV(cp, dt, st)                                                        \
  (*(const bf16x8*)&cp[(((st) >> 1) << 11) + (((dt)*32 + lo5) << 5) +           \
                       (((((st)*2 + g) & 3) ^ swr) << 3)])

#define QK(d0, d1, kc)                                                          \
  do {                                                                          \
    __builtin_amdgcn_s_setprio(1);                                              \
    d0 = z16; d1 = z16;                                                         \
    d0 = mfma32(LDSK(kc, 0, 0), qf0, d0);                                       \
    d0 = mfma32(LDSK(kc, 0, 1), qf1, d0);                                       \
    d0 = mfma32(LDSK(kc, 0, 2), qf2, d0);                                       \
    d0 = mfma32(LDSK(kc, 0, 3), qf3, d0);                                       \
    d1 = mfma32(LDSK(kc, 1, 0), qf0, d1);                                       \
    d1 = mfma32(LDSK(kc, 1, 1), qf1, d1);                                       \
    d1 = mfma32(LDSK(kc, 1, 2), qf2, d1);                                       \
    d1 = mfma32(LDSK(kc, 1, 3), qf3, d1);                                       \
    __builtin_amdgcn_s_setprio(0);                                              \
  } while (0)

#define SOFTMAX(sv, sw)                                                         \
  do {                                                                          \
    float p[16];                                                                \
    _Pragma("unroll") for (int r = 0; r < 16; ++r) p[r] = fexp2(sv[r]);         \
    ps0 += p[0] + p[4] + p[8] + p[12];                                          \
    ps1 += p[1] + p[5] + p[9] + p[13];                                          \
    ps2 += p[2] + p[6] + p[10] + p[14];                                         \
    ps3 += p[3] + p[7] + p[11] + p[15];                                         \
    unsigned pw0 = pack2(p[0], p[1]), pw1 = pack2(p[2], p[3]);                  \
    unsigned pw2 = pack2(p[4], p[5]), pw3 = pack2(p[6], p[7]);                  \
    unsigned pw4 = pack2(p[8], p[9]), pw5 = pack2(p[10], p[11]);                \
    unsigned pw6 = pack2(p[12], p[13]), pw7 = pack2(p[14], p[15]);              \
    uint2v a02 = __builtin_amdgcn_permlane32_swap(pw0, pw2, false, false);      \
    uint2v a13 = __builtin_amdgcn_permlane32_swap(pw1, pw3, false, false);      \
    uint2v a46 = __builtin_amdgcn_permlane32_swap(pw4, pw6, false, false);      \
    uint2v a57 = __builtin_amdgcn_permlane32_swap(pw5, pw7, false, false);      \
    pa0 = mk8(a02.x, a13.x, a02.y, a13.y);                                      \
    pa1 = mk8(a46.x, a57.x, a46.y, a57.y);                                      \
    _Pragma("unroll") for (int r = 0; r < 16; ++r) p[r] = fexp2(sw[r]);         \
    ps0 += p[0] + p[4] + p[8] + p[12];                                          \
    ps1 += p[1] + p[5] + p[9] + p[13];                                          \
    ps2 += p[2] + p[6] + p[10] + p[14];                                         \
    ps3 += p[3] + p[7] + p[11] + p[15];                                         \
    pw0 = pack2(p[0], p[1]); pw1 = pack2(p[2], p[3]);                           \
    pw2 = pack2(p[4], p[5]); pw3 = pack2(p[6], p[7]);                           \
    pw4 = pack2(p[8], p[9]); pw5 = pack2(p[10], p[11]);                         \
    pw6 = pack2(p[12], p[13]); pw7 = pack2(p[14], p[15]);                       \
    a02 = __builtin_amdgcn_permlane32_swap(pw0, pw2, false, false);             \
    a13 = __builtin_amdgcn_permlane32_swap(pw1, pw3, false, false);             \
    a46 = __builtin_amdgcn_permlane32_swap(pw4, pw6, false, false);             \
    a57 = __builtin_amdgcn_permlane32_swap(pw5, pw7, false, false);             \
    pb0 = mk8(a02.x, a13.x, a02.y, a13.y);                                      \
    pb1 = mk8(a46.x, a57.x, a46.y, a57.y);                                      \
  } while (0)

#define PV(vc)                                                                  \
  do {                                                                          \
    __builtin_amdgcn_s_setprio(1);                                              \
    o0 = mfma32(pa0, LDSV(vc, 0, 0), o0);                                       \
    o1 = mfma32(pa0, LDSV(vc, 1, 0), o1);                                       \
    o0 = mfma32(pa1, LDSV(vc, 0, 1), o0);                                       \
    o1 = mfma32(pa1, LDSV(vc, 1, 1), o1);                                       \
    o0 = mfma32(pb0, LDSV(vc, 0, 2), o0);                                       \
    o1 = mfma32(pb0, LDSV(vc, 1, 2), o1);                                       \
    o0 = mfma32(pb1, LDSV(vc, 0, 3), o0);                                       \
    o1 = mfma32(pb1, LDSV(vc, 1, 3), o1);                                       \
    __builtin_amdgcn_s_setprio(0);                                              \
  } while (0)

  const f32x16 z16 = {};
  f32x16 o0 = z16, o1 = z16;
  f32x16 sA0, sA1, sB0, sB1;
  bf16x8 pa0, pa1, pb0, pb1;
  float ps0 = 0.f, ps1 = 0.f, ps2 = 0.f, ps3 = 0.f;

  STAGE(0, 0);
  STAGE(1, 64);
  // vmcnt(6): of 8 outstanding (K0,K0,V0,V0,K1,K1,V1,V1), newest 6 remain
  // -> K0 landed. Barrier makes all waves' K0 parts visible.
  asm volatile("s_waitcnt vmcnt(6)" ::: "memory");
  __builtin_amdgcn_s_barrier();
  __builtin_amdgcn_sched_barrier(0);
  QK(sA0, sA1, Ks[0]);  // tile 0 -> state A

  for (int t = 0; t < 32; t += 2) {
    // ---- step t (even): current = A(tile t), next = B(tile t+1) ----
    if (t < 30) {
      STAGE((t + 2) & 3, (t + 2) * 64);
      // outstanding: V(t)x2 + tile(t+1)x4 + tile(t+2)x4; vmcnt(6) leaves
      // [V(t+1)x2, tile(t+2)x4] -> V(t) and K(t+1) landed.
      asm volatile("s_waitcnt vmcnt(6)" ::: "memory");
    } else {
      asm volatile("s_waitcnt vmcnt(2)" ::: "memory");  // V30 + K31 landed
    }
    __builtin_amdgcn_s_barrier();
    __builtin_amdgcn_sched_barrier(0);
    QK(sB0, sB1, Ks[(t + 1) & 3]);   // tile t+1 (matrix pipe, independent)
    SOFTMAX(sA0, sA1);               // tile t (VALU) - overlaps QK above
    PV(Vs[t & 3]);                   // tile t

    // ---- step t+1 (odd): current = B(tile t+1), next = A(tile t+2) ----
    if (t < 29) {
      STAGE((t + 3) & 3, (t + 3) * 64);
      asm volatile("s_waitcnt vmcnt(6)" ::: "memory");
    } else {
      asm volatile("s_waitcnt vmcnt(0)" ::: "memory");  // V31 landed
    }
    __builtin_amdgcn_s_barrier();
    __builtin_amdgcn_sched_barrier(0);
    if (t < 30) QK(sA0, sA1, Ks[(t + 2) & 3]);  // tile t+2
    SOFTMAX(sB0, sB1);
    PV(Vs[(t + 1) & 3]);
  }
#undef STAGE
#undef LDSK
#undef LDSV
#undef QK
#undef SOFTMAX
#undef PV

  // tot on lane l = softmax denominator for q = q0 + (l&31)
  float plsum = (ps0 + ps1) + (ps2 + ps3);
  float tot = plsum + __shfl_xor(plsum, 32);

#pragma unroll
  for (int r = 0; r < 16; ++r) {
    int qr = (r & 3) + 8 * (r >> 2) + 4 * g;        // output row of o0[r]/o1[r]
    float inv = 1.0f / __shfl(tot, qr);             // row qr's denominator
    bf16* op = AO + (size_t)(b * 2048 + q0 + qr) * 1024 + h * 64 + lo5;
    op[0]  = (bf16)(o0[r] * inv);
    op[32] = (bf16)(o1[r] * inv);
  }
}

// ---------------------------------------------------------------------------
// Kernel 4: output projection, 64x128 tile (512 blocks = 2/CU), m97 structure,
// swizzled LDS. fp32 out + bias.
// ---------------------------------------------------------------------------
__global__ __launch_bounds__(256) void gemm_o(
    const bf16* __restrict__ A, const bf16* __restrict__ Wt3,
    const float* __restrict__ bo, float* __restrict__ C) {
  __shared__ bf16 As[2][64 * 32];
  __shared__ bf16 Bs[2][128 * 32];
  int m0 = blockIdx.x * 64, n0 = blockIdx.y * 128;
  int tid = threadIdx.x, w = tid >> 6, l = tid & 63;
  int wm = (w >> 1) * 32, wn = (w & 1) * 64;
  int c16 = l & 15, g = l >> 4;
  int rsw = (c16 >> 1) & 3;

  // A staging: 1 chunk/lane. row = tid>>2, phys chunk = tid&3
  int arow = tid >> 2, akc = tid & 3;
  int asrc = (akc ^ ((arow >> 1) & 3)) * 8;
  // B staging: 2 chunks/lane
  int brow0 = (w * 2 + 0) * 16 + (l >> 2);
  int brow1 = (w * 2 + 1) * 16 + (l >> 2);
  int bk0 = ((l & 3) ^ ((brow0 >> 1) & 3)) * 8;
  int bk1 = ((l & 3) ^ ((brow1 >> 1) & 3)) * 8;

  f32x4 acc[2][4] = {};

#define STAGE_O(buf, kt)                                                     \
  do {                                                                       \
    gload_lds16(A + (size_t)(m0 + arow) * 1024 + (kt) + asrc,                \
                (char*)As[buf] + tid * 16);                                  \
    gload_lds16(Wt3 + (size_t)(n0 + brow0) * 1024 + (kt) + bk0,              \
                (char*)Bs[buf] + (w * 2 + 0) * 1024 + l * 16);               \
    gload_lds16(Wt3 + (size_t)(n0 + brow1) * 1024 + (kt) + bk1,              \
                (char*)Bs[buf] + (w * 2 + 1) * 1024 + l * 16);               \
  } while (0)

  STAGE_O(0, 0);
  __syncthreads();

  int cur = 0;
  for (int kt = 0; kt < 1024; kt += 32) {
    if (kt < 992) STAGE_O(cur ^ 1, kt + 32);
    bf16x8 af[2], bfr[4];
#pragma unroll
    for (int mt = 0; mt < 2; ++mt)
      af[mt] = *(const bf16x8*)&As[cur][(wm + mt * 16 + c16) * 32 + ((g ^ rsw) * 8)];
#pragma unroll
    for (int nt = 0; nt < 4; ++nt)
      bfr[nt] = *(const bf16x8*)&Bs[cur][(wn + nt * 16 + c16) * 32 + ((g ^ rsw) * 8)];
#pragma unroll
    for (int mt = 0; mt < 2; ++mt)
#pragma unroll
      for (int nt = 0; nt < 4; ++nt)
        acc[mt][nt] = mfma16(af[mt], bfr[nt], acc[mt][nt]);
    __syncthreads();  // drains vmcnt -> next buffer staged
    cur ^= 1;
  }
#undef STAGE_O

#pragma unroll
  for (int mt = 0; mt < 2; ++mt)
#pragma unroll
    for (int nt = 0; nt < 4; ++nt) {
      int n = n0 + wn + nt * 16 + c16;
      float bb = bo[n];
#pragma unroll
      for (int r = 0; r < 4; ++r) {
        int m = m0 + wm + mt * 16 + g * 4 + r;
        C[(size_t)m * 1024 + n] = acc[mt][nt][r] + bb;
      }
    }
}

// ---------------------------------------------------------------------------
extern "C" void kernel_launch(void* const* d_in, const int* in_sizes, int n_in,
                              void* d_out, int out_size, void* d_ws, size_t ws_size,
                              hipStream_t stream) {
  const float* query = (const float*)d_in[0];
  const float* key_  = (const float*)d_in[1];
  const float* value = (const float*)d_in[2];
  const float* Wq = (const float*)d_in[3];
  const float* bq = (const float*)d_in[4];
  const float* Wk = (const float*)d_in[5];
  const float* bk = (const float*)d_in[6];
  const float* Wv = (const float*)d_in[7];
  const float* bv = (const float*)d_in[8];
  const float* Wo = (const float*)d_in[9];
  const float* bo = (const float*)d_in[10];
  float* out = (float*)d_out;

  char* ws = (char*)d_ws;
  const size_t MB = 1024 * 1024;
  bf16* Wt  = (bf16*)(ws);              // 4 x [1024][1024] bf16 = 8 MB
  bf16* Qp  = (bf16*)(ws + 8 * MB);     // [4096][1024] bf16 (pre-scaled)
  bf16* Kp  = (bf16*)(ws + 16 * MB);    // [4096][1024]
  bf16* Vt  = (bf16*)(ws + 24 * MB);    // [32][64][2048]
  bf16* AO  = (bf16*)(ws + 32 * MB);    // attn out [4096][1024]

  wt_kernel<<<dim3(256, 4), dim3(256), 0, stream>>>(Wq, Wk, Wv, Wo, Wt);
  gemm_qkv<<<dim3(32, 8, 3), dim3(256), 0, stream>>>(query, key_, value, Wt,
                                                     bq, bk, bv, Qp, Kp, Vt);
  flash_kernel<<<dim3(512), dim3(256), 0, stream>>>(Qp, Kp, Vt, AO);
  gemm_o<<<dim3(64, 8), dim3(256), 0, stream>>>(AO, Wt + (size_t)3 * 1024 * 1024, bo, out);
}